// Round 1
// baseline (74.710 us; speedup 1.0000x reference)
//
#include <hip/hip_runtime.h>

// Kendall tau: tau = sum_{all i,j} tanh((p_i-p_j)(t_i-t_j)/T) / (n*(n-1))
// (summand symmetric, diagonal zero -> sum over ALL ordered pairs / n(n-1)).
//
// n = 8192. Grid: NBLK blocks each owning a JBLK-wide j-slice; each of the
// TPB threads holds KPT=32 i-values in registers -> full 8192 x 8192 outer
// product. tanh(x) = 1 - 2/(exp2(x*2*log2e)+1) via v_exp_f32 + v_rcp_f32.

#define NTOT 8192
#define JBLK 16
#define NBLK (NTOT / JBLK)   // 512
#define TPB  256
#define KPT  (NTOT / TPB)    // 32

#if __has_builtin(__builtin_amdgcn_exp2f)
#define FAST_EXP2(x) __builtin_amdgcn_exp2f(x)
#else
#define FAST_EXP2(x) exp2f(x)
#endif
#if __has_builtin(__builtin_amdgcn_rcpf)
#define FAST_RCP(x) __builtin_amdgcn_rcpf(x)
#else
#define FAST_RCP(x) (1.0f / (x))
#endif

__global__ __launch_bounds__(TPB) void ktau_partial(const float* __restrict__ pred,
                                                    const float* __restrict__ targ,
                                                    double* __restrict__ partial) {
    // tanh(d/T) with T=0.1: tanh(10*d) = 1 - 2/(exp2(d*C)+1), C = 20/ln(2).
    const float C = 28.853900817779268f;

    __shared__ float sp[JBLK];
    __shared__ float st[JBLK];
    __shared__ double red[TPB];

    const int tid = threadIdx.x;
    const int j0  = blockIdx.x * JBLK;

    if (tid < JBLK) {
        sp[tid] = pred[j0 + tid];
        st[tid] = targ[j0 + tid] * C;   // fold C into t once
    }

    // Each thread's 32 i-values, strided for coalescing.
    float pi[KPT], ti[KPT];
#pragma unroll
    for (int k = 0; k < KPT; ++k) {
        const int i = tid + k * TPB;
        pi[k] = pred[i];
        ti[k] = targ[i] * C;
    }
    __syncthreads();

    double dacc = 0.0;
#pragma unroll 2
    for (int j = 0; j < JBLK; ++j) {
        const float pj = sp[j];   // same addr across lanes -> LDS broadcast
        const float tj = st[j];
        float facc = 0.0f;        // accumulates sum of (-2*r); +1 counted later
#pragma unroll
        for (int k = 0; k < KPT; ++k) {
            const float x = (pi[k] - pj) * (ti[k] - tj);
            const float e = FAST_EXP2(x);            // x>>0 -> inf, x<<0 -> 0 (correct tails)
            const float r = FAST_RCP(e + 1.0f);      // rcp(inf)=0 -> term=+1; rcp(1)=1 -> term=-1
            facc = __builtin_fmaf(-2.0f, r, facc);
        }
        dacc += (double)facc;     // flush per j-row to bound fp32 error
    }
    dacc += (double)(JBLK * KPT); // the "+1" of each of the 512 terms, exactly

    // Block reduction in double.
    red[tid] = dacc;
    __syncthreads();
    for (int s = TPB / 2; s > 0; s >>= 1) {
        if (tid < s) red[tid] += red[tid + s];
        __syncthreads();
    }
    if (tid == 0) partial[blockIdx.x] = red[0];
}

__global__ __launch_bounds__(NBLK) void ktau_final(const double* __restrict__ partial,
                                                   float* __restrict__ out) {
    __shared__ double red[NBLK];
    const int tid = threadIdx.x;
    red[tid] = partial[tid];
    __syncthreads();
    for (int s = NBLK / 2; s > 0; s >>= 1) {
        if (tid < s) red[tid] += red[tid + s];
        __syncthreads();
    }
    if (tid == 0) {
        const double n_ordered_pairs = (double)NTOT * (double)(NTOT - 1);
        out[0] = (float)(red[0] / n_ordered_pairs);
    }
}

extern "C" void kernel_launch(void* const* d_in, const int* in_sizes, int n_in,
                              void* d_out, int out_size, void* d_ws, size_t ws_size,
                              hipStream_t stream) {
    const float* pred = (const float*)d_in[0];
    const float* targ = (const float*)d_in[1];
    float* out = (float*)d_out;
    double* partial = (double*)d_ws;   // NBLK doubles = 4 KB

    ktau_partial<<<NBLK, TPB, 0, stream>>>(pred, targ, partial);
    ktau_final<<<1, NBLK, 0, stream>>>(partial, out);
}

// Round 2
// 71.440 us; speedup vs baseline: 1.0458x; 1.0458x over previous
//
#include <hip/hip_runtime.h>

// Kendall tau: tau = sum_{all ordered i,j} tanh((p_i-p_j)(t_i-t_j)/T) / (n*(n-1))
// (summand symmetric, diagonal exactly zero under this formula).
// tanh(d/T), T=0.1: tanh(10d) = 1 - 2/(exp2(d*C)+1), C = 20/ln(2).
//
// Hot loop: 8 j-values in registers (no LDS), k-outer/j-inner -> 8 independent
// accumulator chains, 16 independent exp/rcp in flight per unroll-2 chunk.
// Floor is the quarter-rate transcendental pipe: 2 trans/pair ~ 6.8 us.

#define NTOT 8192
#define TPB  512
#define KPT  (NTOT / TPB)    // 16 i-values per thread
#define JBLK 8
#define NBLK (NTOT / JBLK)   // 1024 blocks

__global__ __launch_bounds__(TPB) void ktau_partial(const float* __restrict__ pred,
                                                    const float* __restrict__ targ,
                                                    double* __restrict__ partial) {
    const float C = 28.853900817779268f;   // 2*10*log2(e)
    const int tid = threadIdx.x;
    const int j0  = blockIdx.x * JBLK;

    // j-window in registers (uniform across the block; broadcast loads)
    float pj[JBLK], tj[JBLK];
#pragma unroll
    for (int jj = 0; jj < JBLK; ++jj) {
        pj[jj] = pred[j0 + jj];
        tj[jj] = targ[j0 + jj] * C;        // fold C into t once
    }

    // i-window in registers, strided for coalescing
    float pi[KPT], ti[KPT];
#pragma unroll
    for (int k = 0; k < KPT; ++k) {
        const int i = tid + k * TPB;
        pi[k] = pred[i];
        ti[k] = targ[i] * C;
    }

    float acc[JBLK];
#pragma unroll
    for (int jj = 0; jj < JBLK; ++jj) acc[jj] = 0.0f;

#pragma unroll 2
    for (int k = 0; k < KPT; ++k) {
#pragma unroll
        for (int jj = 0; jj < JBLK; ++jj) {
            const float x = (pi[k] - pj[jj]) * (ti[k] - tj[jj]);
            const float e = __builtin_amdgcn_exp2f(x);       // saturates correctly at tails
            const float r = __builtin_amdgcn_rcpf(e + 1.0f); // rcp(inf)=0, rcp(1)=1, rcp(2)=0.5
            acc[jj] = __builtin_fmaf(-2.0f, r, acc[jj]);     // term = 1 - 2r; +1 counted later
        }
    }

    // per-thread fp32 sum (|each acc| <= 32, rounding error ~1e-5 -> negligible on tau)
    float fsum = 0.0f;
#pragma unroll
    for (int jj = 0; jj < JBLK; ++jj) fsum += acc[jj];

    double dacc = (double)fsum;
    // wave(64) shuffle reduction in double
#pragma unroll
    for (int off = 32; off > 0; off >>= 1)
        dacc += __shfl_down(dacc, off, 64);

    __shared__ double red[TPB / 64];
    const int wave = tid >> 6;
    if ((tid & 63) == 0) red[wave] = dacc;
    __syncthreads();
    if (tid == 0) {
        double s = 0.0;
#pragma unroll
        for (int w = 0; w < TPB / 64; ++w) s += red[w];
        // the "+1" of each of the block's TPB*KPT*JBLK terms, added exactly once
        partial[blockIdx.x] = s + (double)(TPB * KPT * JBLK);
    }
}

__global__ __launch_bounds__(256) void ktau_final(const double* __restrict__ partial,
                                                  float* __restrict__ out) {
    const int tid = threadIdx.x;
    double s = partial[tid] + partial[tid + 256] + partial[tid + 512] + partial[tid + 768];
#pragma unroll
    for (int off = 32; off > 0; off >>= 1)
        s += __shfl_down(s, off, 64);
    __shared__ double red[4];
    if ((tid & 63) == 0) red[tid >> 6] = s;
    __syncthreads();
    if (tid == 0) {
        const double t = red[0] + red[1] + red[2] + red[3];
        out[0] = (float)(t / ((double)NTOT * (double)(NTOT - 1)));
    }
}

extern "C" void kernel_launch(void* const* d_in, const int* in_sizes, int n_in,
                              void* d_out, int out_size, void* d_ws, size_t ws_size,
                              hipStream_t stream) {
    const float* pred = (const float*)d_in[0];
    const float* targ = (const float*)d_in[1];
    float* out = (float*)d_out;
    double* partial = (double*)d_ws;   // NBLK doubles = 8 KB

    ktau_partial<<<NBLK, TPB, 0, stream>>>(pred, targ, partial);
    ktau_final<<<1, 256, 0, stream>>>(partial, out);
}